// Round 1
// baseline (216.891 us; speedup 1.0000x reference)
//
#include <hip/hip_runtime.h>

// Problem constants
#define N_B   64
#define T_S   32
#define DIM   12288          // 3*64*64
#define ROWS  2048           // N_B*T_S
#define SEG   32             // split-K segments
#define KSEG  384            // DIM/SEG
#define NCOL  12             // used GEMM columns (3 obj * 4)

// ---------------- Kernel 1: split-K skinny GEMM (12 used columns) ----------
// Grid: 256 blocks (8 row-groups x 32 k-segments), 256 threads.
// lane = row  -> W address is wave-uniform (scalar loads), x streamed per-lane.
__global__ __launch_bounds__(256) void k_gemm(const float* __restrict__ x,
                                              const float* __restrict__ W,
                                              float* __restrict__ part) {
    const int g   = blockIdx.x & 7;     // row group
    const int s   = blockIdx.x >> 3;    // k segment
    const int row = (g << 8) | threadIdx.x;
    const int k0  = s * KSEG;

    const float4* xr = (const float4*)(x + (size_t)row * DIM + k0);

    float acc[NCOL];
#pragma unroll
    for (int c = 0; c < NCOL; ++c) acc[c] = 0.f;

#pragma unroll 2
    for (int j = 0; j < KSEG / 4; ++j) {
        const float4 xv = xr[j];
        const float  xs[4] = { xv.x, xv.y, xv.z, xv.w };
        const float* wr = W + (size_t)(k0 + 4 * j) * 24;
#pragma unroll
        for (int u = 0; u < 4; ++u) {
            const float  xv1 = xs[u];
            const float* w   = wr + u * 24;   // uniform address across wave
            acc[0]  += xv1 * w[0];  acc[1]  += xv1 * w[1];
            acc[2]  += xv1 * w[2];  acc[3]  += xv1 * w[3];
            acc[4]  += xv1 * w[8];  acc[5]  += xv1 * w[9];
            acc[6]  += xv1 * w[10]; acc[7]  += xv1 * w[11];
            acc[8]  += xv1 * w[16]; acc[9]  += xv1 * w[17];
            acc[10] += xv1 * w[18]; acc[11] += xv1 * w[19];
        }
    }
    // part[c][s][row] -> coalesced writes, coalesced reduce reads
#pragma unroll
    for (int c = 0; c < NCOL; ++c)
        part[((size_t)c * SEG + s) * ROWS + row] = acc[c];
}

// ---------------- Kernel 2: reduce partials + bias + sigmoid constrain -----
// 24576 outputs; tid -> (c, row); writes z[b][t][o][c'] flat (row*12 + c).
__global__ __launch_bounds__(256) void k_reduce(const float* __restrict__ part,
                                                const float* __restrict__ b_enc,
                                                float* __restrict__ zbuf) {
    const int tid = blockIdx.x * 256 + threadIdx.x;   // 0..24575
    const int c   = tid >> 11;                        // 0..11 (wave-uniform)
    const int row = tid & 2047;

    float sum = 0.f;
    const float* p = part + (size_t)c * SEG * ROWS + row;
#pragma unroll
    for (int i = 0; i < SEG; ++i) sum += p[(size_t)i * ROWS];

    const int o  = c >> 2;
    const int cp = c & 3;
    sum += b_enc[o * 8 + cp];

    const float sg = 1.f / (1.f + expf(-sum));
    float v;
    if (cp == 0)      v = sg * 0.7f + 0.1f;           // (0.8-0.1)*sig + 0.1
    else if (cp == 1) v = sg * 0.5f + 0.75f;          // (1.25-0.75)*sig + 0.75
    else              v = (2.f * sg - 1.f) * 0.9f;    // pos in [-0.9, 0.9]

    zbuf[row * NCOL + c] = v;
}

// ---------------- Kernel 3: match (serial over T) + fix_supair + output ----
// One block (64 threads) per batch element.
__global__ __launch_bounds__(64) void k_post(const float* __restrict__ zbuf,
                                             float* __restrict__ out) {
    __shared__ float z[T_S * NCOL];    // 384
    __shared__ float zf[T_S * NCOL];   // fixed z
    const int b   = blockIdx.x;
    const int tid = threadIdx.x;

#pragma unroll
    for (int i = 0; i < 6; ++i)
        z[tid + 64 * i] = zbuf[b * 384 + tid + 64 * i];
    __syncthreads();

    if (tid == 0) {
        // prev matched positions (channels 2,3 of each object)
        float px[3] = { z[2], z[6], z[10] };
        float py[3] = { z[3], z[7], z[11] };
        for (int t = 1; t < T_S; ++t) {
            float c[12];
#pragma unroll
            for (int j = 0; j < 12; ++j) c[j] = z[t * 12 + j];
            float e[3][3];
#pragma unroll
            for (int i = 0; i < 3; ++i) {
#pragma unroll
                for (int j = 0; j < 3; ++j) {
                    const float dx = px[i] - c[j * 4 + 2];
                    const float dy = py[i] - c[j * 4 + 3];
                    e[i][j] = dx * dx + dy * dy;
                }
            }
            int idx[3];
#pragma unroll
            for (int i = 0; i < 3; ++i) {       // argmin, first-min tie-break
                int jb = 0; float eb = e[i][0];
                if (e[i][1] < eb) { eb = e[i][1]; jb = 1; }
                if (e[i][2] < eb) { eb = e[i][2]; jb = 2; }
                idx[i] = jb;
            }
            const bool ok = (idx[1] != idx[0]) && (idx[2] != idx[1]) && (idx[0] != idx[2]);
            if (!ok) {                          // greedy assignment
                float used[3] = { 0.f, 0.f, 0.f };
#pragma unroll
                for (int i = 0; i < 3; ++i) {
                    const float e0 = e[i][0] + used[0] * 1e12f;
                    const float e1 = e[i][1] + used[1] * 1e12f;
                    const float e2 = e[i][2] + used[2] * 1e12f;
                    int jb = 0; float eb = e0;
                    if (e1 < eb) { eb = e1; jb = 1; }
                    if (e2 < eb) { eb = e2; jb = 2; }
                    idx[i] = jb;
                    used[jb] += 1.f;
                }
            }
            // permute objects of timestep t in place
#pragma unroll
            for (int k = 0; k < 3; ++k) {
                const int src = idx[k];
                z[t * 12 + k * 4 + 0] = c[src * 4 + 0];
                z[t * 12 + k * 4 + 1] = c[src * 4 + 1];
                z[t * 12 + k * 4 + 2] = c[src * 4 + 2];
                z[t * 12 + k * 4 + 3] = c[src * 4 + 3];
            }
#pragma unroll
            for (int k = 0; k < 3; ++k) {
                px[k] = c[idx[k] * 4 + 2];
                py[k] = c[idx[k] * 4 + 3];
            }
        }
    }
    __syncthreads();

    // fix_supair: zf[t][o][ch] = mask ? smooth : z  (mask from channel ch&1)
#pragma unroll
    for (int ii = 0; ii < 6; ++ii) {
        const int i  = tid + 64 * ii;      // 0..383
        const int t  = i / 12;
        const int j  = i % 12;
        const int o  = j >> 2;
        const int cc = (j & 3) & 1;
        const int mb = o * 4 + cc;
        const float pd = (t >= 1)  ? fabsf(z[t * 12 + mb] - z[(t - 1) * 12 + mb]) : 0.f;
        const float ad = (t <= 30) ? fabsf(z[(t + 1) * 12 + mb] - z[t * 12 + mb]) : 0.f;
        const bool  m  = (pd > 0.095f) && (ad > 0.095f);
        const float sm = (t >= 1 && t <= 30)
                             ? (z[(t - 1) * 12 + j] + z[(t + 1) * 12 + j]) * 0.5f
                             : 0.f;
        zf[i] = m ? sm : z[t * 12 + j];
    }
    __syncthreads();

    // output: (64, 31, 3, 4); ch 0:2 = zf[t+1,·,2:4]+1 ; ch 2:4 = 10*(zf[t+1]-zf[t])[2:4]
    for (int i = tid; i < 31 * 12; i += 64) {
        const int t  = i / 12;
        const int j  = i % 12;
        const int o  = j >> 2;
        const int c2 = j & 3;
        const int pb = o * 4 + 2 + (c2 & 1);   // position channel 2 or 3
        float v;
        if (c2 < 2) v = zf[(t + 1) * 12 + pb] + 1.f;
        else        v = (zf[(t + 1) * 12 + pb] - zf[t * 12 + pb]) * 10.f;
        out[b * 372 + i] = v;
    }
}

extern "C" void kernel_launch(void* const* d_in, const int* in_sizes, int n_in,
                              void* d_out, int out_size, void* d_ws, size_t ws_size,
                              hipStream_t stream) {
    (void)in_sizes; (void)n_in; (void)out_size; (void)ws_size;
    const float* x     = (const float*)d_in[0];
    const float* W_enc = (const float*)d_in[1];
    const float* b_enc = (const float*)d_in[2];
    float* out  = (float*)d_out;

    float* zbuf = (float*)d_ws;            // 24576 floats
    float* part = zbuf + ROWS * NCOL;      // 12*32*2048 = 786432 floats (~3 MB)

    k_gemm  <<<SEG * 8, 256, 0, stream>>>(x, W_enc, part);
    k_reduce<<<(ROWS * NCOL) / 256, 256, 0, stream>>>(part, b_enc, zbuf);
    k_post  <<<N_B, 64, 0, stream>>>(zbuf, out);
}

// Round 2
// 175.760 us; speedup vs baseline: 1.2340x; 1.2340x over previous
//
#include <hip/hip_runtime.h>

#define N_B   64
#define T_S   32
#define DIM   12288          // 3*64*64
#define ROWS  2048           // N_B*T_S
#define NCOL  12             // used GEMM columns (3 obj * 4)
#define RPB   4              // rows per block
#define TILE  1024           // k covered per tile (256 thr * float4)
#define NTILE (DIM / TILE)   // 12

// ---------------- Kernel 0: transpose used W columns -> Wt[c][k] -----------
// Wt[c*DIM + k] = W[k*24 + (c>>2)*8 + (c&3)]
__global__ __launch_bounds__(256) void k_tw(const float* __restrict__ W,
                                            float* __restrict__ Wt) {
    const int idx = blockIdx.x * 256 + threadIdx.x;   // 0 .. 147455
    const int c   = idx / DIM;
    const int k   = idx - c * DIM;
    const int cm  = ((c >> 2) << 3) | (c & 3);
    Wt[idx] = W[k * 24 + cm];
}

// ---------------- Kernel 1: coalesced skinny GEMM + constrain --------------
// Block = 4 rows x full K. 256 threads span K (contiguous float4 per lane).
// x read once (coalesced); Wt reused across 4 rows (L2-resident).
__global__ __launch_bounds__(256, 2) void k_gemm(const float* __restrict__ x,
                                                 const float* __restrict__ Wt,
                                                 const float* __restrict__ b_enc,
                                                 float* __restrict__ zbuf) {
    const int r0  = blockIdx.x * RPB;
    const int tid = threadIdx.x;

    float acc[RPB][NCOL];
#pragma unroll
    for (int r = 0; r < RPB; ++r)
#pragma unroll
        for (int c = 0; c < NCOL; ++c) acc[r][c] = 0.f;

#pragma unroll 2
    for (int t = 0; t < NTILE; ++t) {
        const int kb = t * TILE + tid * 4;
        float4 wv[NCOL];
#pragma unroll
        for (int c = 0; c < NCOL; ++c)
            wv[c] = *(const float4*)(Wt + (size_t)c * DIM + kb);
        float4 xv[RPB];
#pragma unroll
        for (int r = 0; r < RPB; ++r)
            xv[r] = *(const float4*)(x + (size_t)(r0 + r) * DIM + kb);
#pragma unroll
        for (int r = 0; r < RPB; ++r)
#pragma unroll
            for (int c = 0; c < NCOL; ++c)
                acc[r][c] += xv[r].x * wv[c].x + xv[r].y * wv[c].y +
                             xv[r].z * wv[c].z + xv[r].w * wv[c].w;
    }

    // wave-level butterfly reduction of all 48 accumulators
#pragma unroll
    for (int r = 0; r < RPB; ++r)
#pragma unroll
        for (int c = 0; c < NCOL; ++c) {
            float v = acc[r][c];
            v += __shfl_xor(v, 32, 64);
            v += __shfl_xor(v, 16, 64);
            v += __shfl_xor(v, 8, 64);
            v += __shfl_xor(v, 4, 64);
            v += __shfl_xor(v, 2, 64);
            v += __shfl_xor(v, 1, 64);
            acc[r][c] = v;
        }

    __shared__ float red[4][RPB * NCOL];
    const int wave = tid >> 6;
    const int lane = tid & 63;
    if (lane == 0) {
#pragma unroll
        for (int r = 0; r < RPB; ++r)
#pragma unroll
            for (int c = 0; c < NCOL; ++c)
                red[wave][r * NCOL + c] = acc[r][c];
    }
    __syncthreads();

    if (tid < RPB * NCOL) {
        float s = red[0][tid] + red[1][tid] + red[2][tid] + red[3][tid];
        const int r  = tid / NCOL;
        const int c  = tid - r * NCOL;
        const int o  = c >> 2;
        const int cp = c & 3;
        s += b_enc[o * 8 + cp];
        const float sg = 1.f / (1.f + expf(-s));
        float v;
        if (cp == 0)      v = sg * 0.7f + 0.1f;
        else if (cp == 1) v = sg * 0.5f + 0.75f;
        else              v = (2.f * sg - 1.f) * 0.9f;
        zbuf[(size_t)(r0 + r) * NCOL + c] = v;
    }
}

// ---------------- Kernel 2: match + fix_supair + output --------------------
// One block (64 threads) per batch. Lane 0 computes only permutation CODES
// (VALU chain; z in LDS is never mutated so its reads pipeline), then all
// lanes apply the permutation, fix, and output.
__global__ __launch_bounds__(64) void k_post(const float* __restrict__ zbuf,
                                             float* __restrict__ out) {
    __shared__ float z[T_S * NCOL];    // raw constrained z
    __shared__ float zm[T_S * NCOL];   // matched
    __shared__ float zf[T_S * NCOL];   // fixed
    __shared__ int   perm[T_S];
    const int b   = blockIdx.x;
    const int tid = threadIdx.x;

#pragma unroll
    for (int i = 0; i < 6; ++i)
        z[tid + 64 * i] = zbuf[b * 384 + tid + 64 * i];
    __syncthreads();

    if (tid == 0) {
        float px0 = z[2],  py0 = z[3];
        float px1 = z[6],  py1 = z[7];
        float px2 = z[10], py2 = z[11];
        for (int t = 1; t < T_S; ++t) {
            const int base = t * 12;
            const float cx0 = z[base + 2],  cy0 = z[base + 3];
            const float cx1 = z[base + 6],  cy1 = z[base + 7];
            const float cx2 = z[base + 10], cy2 = z[base + 11];

            float dx, dy;
            dx = px0 - cx0; dy = py0 - cy0; const float e00 = dx * dx + dy * dy;
            dx = px0 - cx1; dy = py0 - cy1; const float e01 = dx * dx + dy * dy;
            dx = px0 - cx2; dy = py0 - cy2; const float e02 = dx * dx + dy * dy;
            dx = px1 - cx0; dy = py1 - cy0; const float e10 = dx * dx + dy * dy;
            dx = px1 - cx1; dy = py1 - cy1; const float e11 = dx * dx + dy * dy;
            dx = px1 - cx2; dy = py1 - cy2; const float e12 = dx * dx + dy * dy;
            dx = px2 - cx0; dy = py2 - cy0; const float e20 = dx * dx + dy * dy;
            dx = px2 - cx1; dy = py2 - cy1; const float e21 = dx * dx + dy * dy;
            dx = px2 - cx2; dy = py2 - cy2; const float e22 = dx * dx + dy * dy;

            auto amin3 = [](float a0, float a1, float a2) {
                int j = 0; float e = a0;
                if (a1 < e) { e = a1; j = 1; }
                if (a2 < e) { j = 2; }
                return j;
            };
            int i0 = amin3(e00, e01, e02);
            int i1 = amin3(e10, e11, e12);
            int i2 = amin3(e20, e21, e22);
            const bool ok = (i1 != i0) && (i2 != i1) && (i0 != i2);
            if (!ok) {
                float u0 = 0.f, u1 = 0.f, u2 = 0.f;
                i0 = amin3(e00, e01, e02);
                if (i0 == 0) u0 = 1.f; else if (i0 == 1) u1 = 1.f; else u2 = 1.f;
                i1 = amin3(e10 + u0 * 1e12f, e11 + u1 * 1e12f, e12 + u2 * 1e12f);
                if (i1 == 0) u0 = 1.f; else if (i1 == 1) u1 = 1.f; else u2 = 1.f;
                i2 = amin3(e20 + u0 * 1e12f, e21 + u1 * 1e12f, e22 + u2 * 1e12f);
            }
            perm[t] = i0 * 9 + i1 * 3 + i2;
            px0 = (i0 == 0) ? cx0 : (i0 == 1) ? cx1 : cx2;
            py0 = (i0 == 0) ? cy0 : (i0 == 1) ? cy1 : cy2;
            px1 = (i1 == 0) ? cx0 : (i1 == 1) ? cx1 : cx2;
            py1 = (i1 == 0) ? cy0 : (i1 == 1) ? cy1 : cy2;
            px2 = (i2 == 0) ? cx0 : (i2 == 1) ? cx1 : cx2;
            py2 = (i2 == 0) ? cy0 : (i2 == 1) ? cy1 : cy2;
        }
    }
    __syncthreads();

    // apply permutation: zm[t][k][ch] = z[t][perm_t(k)][ch]
#pragma unroll
    for (int ii = 0; ii < 6; ++ii) {
        const int i  = tid + 64 * ii;    // 0..383
        const int t  = i / 12;
        const int j  = i - t * 12;
        const int k  = j >> 2;
        const int ch = j & 3;
        int p = k;
        if (t > 0) {
            const int code = perm[t];
            p = (k == 0) ? code / 9 : (k == 1) ? (code % 9) / 3 : code % 3;
        }
        zm[i] = z[t * 12 + p * 4 + ch];
    }
    __syncthreads();

    // fix_supair
#pragma unroll
    for (int ii = 0; ii < 6; ++ii) {
        const int i  = tid + 64 * ii;
        const int t  = i / 12;
        const int j  = i - t * 12;
        const int o  = j >> 2;
        const int cc = j & 1;
        const int mb = o * 4 + cc;
        const float pd = (t >= 1)  ? fabsf(zm[t * 12 + mb] - zm[(t - 1) * 12 + mb]) : 0.f;
        const float ad = (t <= 30) ? fabsf(zm[(t + 1) * 12 + mb] - zm[t * 12 + mb]) : 0.f;
        const bool  m  = (pd > 0.095f) && (ad > 0.095f);
        const float sm = (t >= 1 && t <= 30)
                             ? (zm[(t - 1) * 12 + j] + zm[(t + 1) * 12 + j]) * 0.5f
                             : 0.f;
        zf[i] = m ? sm : zm[t * 12 + j];
    }
    __syncthreads();

    // output (64, 31, 3, 4)
    for (int i = tid; i < 31 * 12; i += 64) {
        const int t  = i / 12;
        const int j  = i - t * 12;
        const int o  = j >> 2;
        const int c2 = j & 3;
        const int pb = o * 4 + 2 + (c2 & 1);
        float v;
        if (c2 < 2) v = zf[(t + 1) * 12 + pb] + 1.f;
        else        v = (zf[(t + 1) * 12 + pb] - zf[t * 12 + pb]) * 10.f;
        out[b * 372 + i] = v;
    }
}

extern "C" void kernel_launch(void* const* d_in, const int* in_sizes, int n_in,
                              void* d_out, int out_size, void* d_ws, size_t ws_size,
                              hipStream_t stream) {
    (void)in_sizes; (void)n_in; (void)out_size; (void)ws_size;
    const float* x     = (const float*)d_in[0];
    const float* W_enc = (const float*)d_in[1];
    const float* b_enc = (const float*)d_in[2];
    float* out  = (float*)d_out;

    float* zbuf = (float*)d_ws;               // 24576 floats
    float* Wt   = zbuf + ROWS * NCOL;         // 147456 floats (~576 KB)

    k_tw  <<<(NCOL * DIM) / 256, 256, 0, stream>>>(W_enc, Wt);
    k_gemm<<<ROWS / RPB, 256, 0, stream>>>(x, Wt, b_enc, zbuf);
    k_post<<<N_B, 64, 0, stream>>>(zbuf, out);
}